// Round 1
// baseline (552.427 us; speedup 1.0000x reference)
//
#include <hip/hip_runtime.h>
#include <hip/hip_bf16.h>

#define NN   20000
#define NE   320000
#define HID  256
#define EDIM 128
#define DDIM 64
#define TDIM 256
#define INCH 704

typedef __attribute__((ext_vector_type(8))) short bf16x8;
typedef __attribute__((ext_vector_type(4))) float f32x4;
typedef __attribute__((ext_vector_type(4))) unsigned int u32x4;

__device__ __forceinline__ unsigned short f2bu(float x) {
    return __bfloat16_as_ushort(__float2bfloat16(x));
}
__device__ __forceinline__ unsigned pk2(float lo, float hi) {
    return (unsigned)f2bu(lo) | ((unsigned)f2bu(hi) << 16);
}
__device__ __forceinline__ float ulo(unsigned u) {
    return __bfloat162float(__ushort_as_bfloat16((unsigned short)(u & 0xffffu)));
}
__device__ __forceinline__ float uhi(unsigned u) {
    return __bfloat162float(__ushort_as_bfloat16((unsigned short)(u >> 16)));
}
__device__ __forceinline__ float silu_f(float x) {
    return x / (1.0f + __expf(-x));
}

// Pack fp32 [K][Nc] row-major weight into bf16 MFMA B-fragment order:
// frag element j of lane l of tile (kt,nt) = B[kt*32 + (l>>4)*8 + j][nt*16 + (l&15)]
// stored at dst[((kt*NT+nt)*64 + l)*8 + j]. Same (l>>4, j)->k mapping is used for
// the A staging, so any HW within-tile K permutation cancels.
__global__ void pack_weights(const float* __restrict__ src, unsigned short* __restrict__ dst,
                             int K, int Nc) {
    int KT = K >> 5, NT = Nc >> 4;
    int total = KT * NT * 64;
    int idx = blockIdx.x * blockDim.x + threadIdx.x;
    if (idx >= total) return;
    int lane = idx & 63;
    int tile = idx >> 6;
    int nt = tile % NT, kt = tile / NT;
    int n = nt * 16 + (lane & 15);
    int k0 = kt * 32 + (lane >> 4) * 8;
    alignas(16) unsigned short v[8];
#pragma unroll
    for (int j = 0; j < 8; ++j) v[j] = f2bu(src[(size_t)(k0 + j) * Nc + n]);
    *reinterpret_cast<u32x4*>(dst + (size_t)idx * 8) = *reinterpret_cast<const u32x4*>(v);
}

__global__ void init_out(const float* __restrict__ pos, float* __restrict__ out, int n) {
    int i = blockIdx.x * blockDim.x + threadIdx.x;
    if (i < n) out[i] = pos[i];
}

__global__ __launch_bounds__(256, 2) void edge_kernel(
    const float* __restrict__ h, const float* __restrict__ pos,
    const float* __restrict__ edge_attr, const float* __restrict__ dist,
    const float* __restrict__ time_emb, const int* __restrict__ edge_index,
    const float* __restrict__ b_time, const float* __restrict__ b_in,
    const float* __restrict__ b_c1, const float* __restrict__ W_c2,
    const float* __restrict__ coord_scale,
    const unsigned short* __restrict__ pWtime, const unsigned short* __restrict__ pWin,
    const unsigned short* __restrict__ pWc1,
    float* __restrict__ out)
{
    __shared__ __align__(16) __hip_bfloat16 sX[2][64][40];   // A-chunk double buffer (80B rows)
    __shared__ __align__(16) __hip_bfloat16 sU[64][264];     // FiLM'd LN output (528B rows)
    __shared__ float sSum[64], sSq[64], sS[64];
    __shared__ int sRow[64], sCol[64];

    const int tid = threadIdx.x;
    const int wave = tid >> 6, lane = tid & 63;
    const int lq = lane >> 4, lr = lane & 15;
    const int e0 = blockIdx.x * 64;
    const int el = tid >> 2, part = tid & 3;

    if (tid < 64) {
        sRow[tid] = edge_index[e0 + tid];
        sCol[tid] = edge_index[NE + e0 + tid];
        sSum[tid] = 0.f; sSq[tid] = 0.f; sS[tid] = 0.f;
    }

    // ---------------- Phase T: T = silu(time_emb) @ W_time  (64x512) ----------------
    auto stageT = [&](int kt, int buf) {
        const float* p = time_emb + (size_t)(e0 + el) * TDIM + kt * 32 + part * 8;
        float4 a = *reinterpret_cast<const float4*>(p);
        float4 b = *reinterpret_cast<const float4*>(p + 4);
        u32x4 w;
        w.x = pk2(silu_f(a.x), silu_f(a.y));
        w.y = pk2(silu_f(a.z), silu_f(a.w));
        w.z = pk2(silu_f(b.x), silu_f(b.y));
        w.w = pk2(silu_f(b.z), silu_f(b.w));
        *reinterpret_cast<u32x4*>(&sX[buf][el][part * 8]) = w;
    };

    f32x4 accT[4][8];
#pragma unroll
    for (int m = 0; m < 4; ++m)
#pragma unroll
        for (int n = 0; n < 8; ++n) accT[m][n] = (f32x4){0.f, 0.f, 0.f, 0.f};

    stageT(0, 0);
    for (int kt = 0; kt < 8; ++kt) {
        __syncthreads();
        if (kt < 7) stageT(kt + 1, (kt + 1) & 1);
        bf16x8 afr[4];
#pragma unroll
        for (int m = 0; m < 4; ++m)
            afr[m] = *reinterpret_cast<const bf16x8*>(&sX[kt & 1][m * 16 + lr][lq * 8]);
#pragma unroll
        for (int n = 0; n < 8; ++n) {
            int ntg = (n < 4) ? (4 * wave + n) : (16 + 4 * wave + (n - 4));
            bf16x8 bfr = *reinterpret_cast<const bf16x8*>(pWtime + ((size_t)(kt * 32 + ntg) * 64 + lane) * 8);
#pragma unroll
            for (int m = 0; m < 4; ++m)
                accT[m][n] = __builtin_amdgcn_mfma_f32_16x16x32_bf16(afr[m], bfr, accT[m][n], 0, 0, 0);
        }
    }

    // add b_time, pack T to bf16 pairs (keeps register pressure down)
    unsigned TP[4][8][2];
#pragma unroll
    for (int n = 0; n < 8; ++n) {
        int colg = (n < 4) ? ((4 * wave + n) * 16 + lr) : (256 + (4 * wave + (n - 4)) * 16 + lr);
        float bt = b_time[colg];
#pragma unroll
        for (int m = 0; m < 4; ++m) {
            f32x4 v = accT[m][n];
            TP[m][n][0] = pk2(v.x + bt, v.y + bt);
            TP[m][n][1] = pk2(v.z + bt, v.w + bt);
        }
    }

    // ---------------- Phase 1: Y = X @ W_in  (64x256), X = [h[row]|h[col]|ea|dist] ----------------
    auto stage1 = [&](int kt, int buf) {
        const float* p;
        if (kt < 8)       p = h + (size_t)sRow[el] * HID + kt * 32;
        else if (kt < 16) p = h + (size_t)sCol[el] * HID + (kt - 8) * 32;
        else if (kt < 20) p = edge_attr + (size_t)(e0 + el) * EDIM + (kt - 16) * 32;
        else              p = dist + (size_t)(e0 + el) * DDIM + (kt - 20) * 32;
        p += part * 8;
        float4 a = *reinterpret_cast<const float4*>(p);
        float4 b = *reinterpret_cast<const float4*>(p + 4);
        u32x4 w;
        w.x = pk2(a.x, a.y); w.y = pk2(a.z, a.w);
        w.z = pk2(b.x, b.y); w.w = pk2(b.z, b.w);
        *reinterpret_cast<u32x4*>(&sX[buf][el][part * 8]) = w;
    };

    f32x4 accY[4][4];
#pragma unroll
    for (int m = 0; m < 4; ++m)
#pragma unroll
        for (int n = 0; n < 4; ++n) accY[m][n] = (f32x4){0.f, 0.f, 0.f, 0.f};

    stage1(0, 0);
    for (int kt = 0; kt < 22; ++kt) {
        __syncthreads();
        if (kt < 21) stage1(kt + 1, (kt + 1) & 1);
        bf16x8 afr[4];
#pragma unroll
        for (int m = 0; m < 4; ++m)
            afr[m] = *reinterpret_cast<const bf16x8*>(&sX[kt & 1][m * 16 + lr][lq * 8]);
#pragma unroll
        for (int n = 0; n < 4; ++n) {
            int ntg = 4 * wave + n;
            bf16x8 bfr = *reinterpret_cast<const bf16x8*>(pWin + ((size_t)(kt * 16 + ntg) * 64 + lane) * 8);
#pragma unroll
            for (int m = 0; m < 4; ++m)
                accY[m][n] = __builtin_amdgcn_mfma_f32_16x16x32_bf16(afr[m], bfr, accY[m][n], 0, 0, 0);
        }
    }

    // + b_in
#pragma unroll
    for (int n = 0; n < 4; ++n) {
        float bi = b_in[(4 * wave + n) * 16 + lr];
#pragma unroll
        for (int m = 0; m < 4; ++m) {
            accY[m][n].x += bi; accY[m][n].y += bi; accY[m][n].z += bi; accY[m][n].w += bi;
        }
    }

    // LayerNorm stats: per-edge sum/sumsq over 256 cols (4 waves x 64 cols each)
#pragma unroll
    for (int m = 0; m < 4; ++m) {
#pragma unroll
        for (int r = 0; r < 4; ++r) {
            float v0 = accY[m][0][r], v1 = accY[m][1][r], v2 = accY[m][2][r], v3 = accY[m][3][r];
            float s1 = v0 + v1 + v2 + v3;
            float s2 = v0 * v0 + v1 * v1 + v2 * v2 + v3 * v3;
#pragma unroll
            for (int off = 1; off < 16; off <<= 1) {
                s1 += __shfl_xor(s1, off, 64);
                s2 += __shfl_xor(s2, off, 64);
            }
            if (lr == 0) {
                atomicAdd(&sSum[m * 16 + lq * 4 + r], s1);
                atomicAdd(&sSq[m * 16 + lq * 4 + r], s2);
            }
        }
    }
    __syncthreads();

    // apply LN + FiLM, write U (bf16) to LDS for GEMM2's A operand
#pragma unroll
    for (int m = 0; m < 4; ++m) {
#pragma unroll
        for (int r = 0; r < 4; ++r) {
            int e = m * 16 + lq * 4 + r;
            float mu = sSum[e] * (1.0f / 256.0f);
            float var = sSq[e] * (1.0f / 256.0f) - mu * mu;
            float rs = rsqrtf(var + 1e-6f);
#pragma unroll
            for (int n = 0; n < 4; ++n) {
                float y = accY[m][n][r];
                float ln = (y - mu) * rs;
                unsigned ush = TP[m][n][r >> 1];
                unsigned usc = TP[m][n + 4][r >> 1];
                float sh = (r & 1) ? uhi(ush) : ulo(ush);
                float sc = (r & 1) ? uhi(usc) : ulo(usc);
                float u = ln * (1.0f + sc) + sh;
                sU[e][(4 * wave + n) * 16 + lr] = __float2bfloat16(u);
            }
        }
    }
    __syncthreads();

    // ---------------- Phase 2: Z = U @ W_c1  (64x256) ----------------
    f32x4 accZ[4][4];
#pragma unroll
    for (int m = 0; m < 4; ++m)
#pragma unroll
        for (int n = 0; n < 4; ++n) accZ[m][n] = (f32x4){0.f, 0.f, 0.f, 0.f};

    for (int kt = 0; kt < 8; ++kt) {
        bf16x8 afr[4];
#pragma unroll
        for (int m = 0; m < 4; ++m)
            afr[m] = *reinterpret_cast<const bf16x8*>(&sU[m * 16 + lr][kt * 32 + lq * 8]);
#pragma unroll
        for (int n = 0; n < 4; ++n) {
            int ntg = 4 * wave + n;
            bf16x8 bfr = *reinterpret_cast<const bf16x8*>(pWc1 + ((size_t)(kt * 16 + ntg) * 64 + lane) * 8);
#pragma unroll
            for (int m = 0; m < 4; ++m)
                accZ[m][n] = __builtin_amdgcn_mfma_f32_16x16x32_bf16(afr[m], bfr, accZ[m][n], 0, 0, 0);
        }
    }

    // s = silu(Z + b_c1) @ W_c2  (per-edge scalar)
#pragma unroll
    for (int m = 0; m < 4; ++m) {
        float ps0 = 0.f, ps1 = 0.f, ps2 = 0.f, ps3 = 0.f;
#pragma unroll
        for (int n = 0; n < 4; ++n) {
            int colg = (4 * wave + n) * 16 + lr;
            float bc = b_c1[colg];
            float w2 = W_c2[colg];
            ps0 += silu_f(accZ[m][n][0] + bc) * w2;
            ps1 += silu_f(accZ[m][n][1] + bc) * w2;
            ps2 += silu_f(accZ[m][n][2] + bc) * w2;
            ps3 += silu_f(accZ[m][n][3] + bc) * w2;
        }
        float ps[4] = {ps0, ps1, ps2, ps3};
#pragma unroll
        for (int r = 0; r < 4; ++r) {
            float v = ps[r];
#pragma unroll
            for (int off = 1; off < 16; off <<= 1) v += __shfl_xor(v, off, 64);
            if (lr == 0) atomicAdd(&sS[m * 16 + lq * 4 + r], v);
        }
    }
    __syncthreads();

    // ---------------- epilogue: coord update + segment-sum via atomics ----------------
    if (tid < 64) {
        int e = tid;
        float inv = tanhf(sS[e]);
        int rI = sRow[e], cI = sCol[e];
        float dx = pos[rI * 3 + 0] - pos[cI * 3 + 0];
        float dy = pos[rI * 3 + 1] - pos[cI * 3 + 1];
        float dz = pos[rI * 3 + 2] - pos[cI * 3 + 2];
        float nrm = sqrtf(dx * dx + dy * dy + dz * dz);
        float f = coord_scale[0] * inv / fmaxf(nrm, 1e-8f);
        atomicAdd(&out[rI * 3 + 0], dx * f);
        atomicAdd(&out[rI * 3 + 1], dy * f);
        atomicAdd(&out[rI * 3 + 2], dz * f);
    }
}

extern "C" void kernel_launch(void* const* d_in, const int* in_sizes, int n_in,
                              void* d_out, int out_size, void* d_ws, size_t ws_size,
                              hipStream_t stream) {
    const float* h          = (const float*)d_in[0];
    const float* pos        = (const float*)d_in[1];
    const float* edge_attr  = (const float*)d_in[2];
    const float* dist       = (const float*)d_in[3];
    const float* time_emb   = (const float*)d_in[4];
    const int*   edge_index = (const int*)d_in[5];
    const float* W_time     = (const float*)d_in[6];
    const float* b_time     = (const float*)d_in[7];
    const float* W_in       = (const float*)d_in[8];
    const float* b_in       = (const float*)d_in[9];
    const float* W_c1       = (const float*)d_in[10];
    const float* b_c1       = (const float*)d_in[11];
    const float* W_c2       = (const float*)d_in[12];
    const float* coord_scale= (const float*)d_in[13];
    float* out = (float*)d_out;

    unsigned short* pWin   = (unsigned short*)d_ws;                       // 704*256*2 = 360448 B
    unsigned short* pWtime = (unsigned short*)((char*)d_ws + 360448);     // 256*512*2 = 262144 B
    unsigned short* pWc1   = (unsigned short*)((char*)d_ws + 622592);     // 256*256*2 = 131072 B

    pack_weights<<<88, 256, 0, stream>>>(W_in,   pWin,   INCH, HID);
    pack_weights<<<64, 256, 0, stream>>>(W_time, pWtime, TDIM, 2 * HID);
    pack_weights<<<32, 256, 0, stream>>>(W_c1,   pWc1,   HID,  HID);
    init_out<<<(3 * NN + 255) / 256, 256, 0, stream>>>(pos, out, 3 * NN);

    edge_kernel<<<NE / 64, 256, 0, stream>>>(
        h, pos, edge_attr, dist, time_emb, edge_index,
        b_time, b_in, b_c1, W_c2, coord_scale,
        pWtime, pWin, pWc1, out);
}